// Round 11
// baseline (222.003 us; speedup 1.0000x reference)
//
#include <hip/hip_runtime.h>

#define NN 50000
#define NE 800000
#define NPAD 50176
// dims: IN=256, HID=128, OUT=64
#define NFS 64        // fill slices (= hist slices)
#define ESL 12500     // NE / NFS (fill)
#define NHS 64        // hist slices
#define EHS 12500     // NE / NHS
#define HPN 25088     // hist nodes per part (2 parts)
#define HPW 12544     // packed words per part (49 KB LDS)
#define FPN 12544     // fill nodes per part (4 parts, 49 KB LDS)
#define FB 256        // fill blocks = 64 slices x 4 parts
#define GB2 196       // gemm blocks = ceil(NN/256)
#define NB 196        // node blocks = ceil(NN/256)

typedef __attribute__((ext_vector_type(8))) short bf16x8;
typedef __attribute__((ext_vector_type(4))) float f32x4;

__device__ __forceinline__ float u2f(unsigned u) { return __uint_as_float(u); }
__device__ __forceinline__ unsigned f2u(float f) { return __float_as_uint(f); }
__device__ __forceinline__ unsigned short f2bf(float f) {
    unsigned u = f2u(f);
    return (unsigned short)((u + (((u >> 16) & 1u) + 0x7fffu)) >> 16);  // RNE
}
// unpack-accumulate one dword-x4 (8 bf16) into 8 fp32 accumulators
__device__ __forceinline__ void acc8(float* ax, uint4 u) {
    ax[0] += u2f(u.x << 16); ax[1] += u2f(u.x & 0xffff0000u);
    ax[2] += u2f(u.y << 16); ax[3] += u2f(u.y & 0xffff0000u);
    ax[4] += u2f(u.z << 16); ax[5] += u2f(u.z & 0xffff0000u);
    ax[6] += u2f(u.w << 16); ax[7] += u2f(u.w & 0xffff0000u);
}
// async global->LDS 16B (dest = wave-uniform base; HW adds lane*16)
#define GLOAD_LDS16(GP, LP)                                              \
    __builtin_amdgcn_global_load_lds(                                    \
        (const __attribute__((address_space(1))) unsigned*)(GP),         \
        (__attribute__((address_space(3))) unsigned*)(LP), 16, 0, 0)

// ------------- fused: 64-slice packed-ushort LDS histogram + W pre-transform -
// Blocks [0,256): hist role — b = part*128 + slice*2 + side (all 256 CUs).
// Blocks [256,296): wtrans role — fragment-order W1/W2 into bf16 hi/lo.
__global__ __launch_bounds__(1024) void hist_wtrans_kernel(
    const int* __restrict__ src, const int* __restrict__ dst,
    unsigned* __restrict__ cnt_sl,
    const float* __restrict__ W1, const float* __restrict__ W2,
    unsigned short* __restrict__ Wh1, unsigned short* __restrict__ Wl1,
    unsigned short* __restrict__ Wh2, unsigned short* __restrict__ Wl2,
    int* __restrict__ done_cnt) {
    if (blockIdx.x == 0 && threadIdx.x == 0) *done_cnt = 0;  // re-zero each replay
    const int b = blockIdx.x;
    if (b >= 256) {  // wtrans role
        float w;
        unsigned short *ph, *pl;
        int f;
        if (b < 288) {  // W1: K=256, N=128 (32768 elems, 32 blocks)
            int i = (b - 256) * 1024 + threadIdx.x;
            int k = i >> 7, n = i & 127;
            f = (((n >> 4) * 32 + (k >> 3)) * 16 + (n & 15)) * 8 + (k & 7);
            w = W1[i]; ph = Wh1; pl = Wl1;
        } else {        // W2: K=128, N=64 (8192 elems, 8 blocks)
            int i = (b - 288) * 1024 + threadIdx.x;
            int k = i >> 6, n = i & 63;
            f = (((n >> 4) * 16 + (k >> 3)) * 16 + (n & 15)) * 8 + (k & 7);
            w = W2[i]; ph = Wh2; pl = Wl2;
        }
        unsigned u = f2u(w);
        float lo = w - u2f(u & 0xffff0000u);
        ph[f] = (unsigned short)(u >> 16);
        pl[f] = (unsigned short)(f2u(lo) >> 16);
        return;
    }
    // hist role
    __shared__ unsigned lcnt[HPW];
    const int side = b & 1;
    const int slice = (b >> 1) & (NHS - 1);
    const int part = b >> 7;
    const int* __restrict__ arr = side ? dst : src;
    const int base = part * HPN;
    for (int j = threadIdx.x; j < HPW; j += 1024) lcnt[j] = 0;
    __syncthreads();
    const int e0 = slice * EHS;
    for (int i = e0 + threadIdx.x; i < e0 + EHS; i += 1024) {
        int v = arr[i] - base;
        if ((unsigned)v < (unsigned)HPN)
            atomicAdd(&lcnt[v >> 1], 1u << ((v & 1) * 16));
    }
    __syncthreads();
    unsigned* o = cnt_sl + (size_t)b * HPW;
    for (int j = threadIdx.x; j < HPW; j += 1024) o[j] = lcnt[j];
}

// ------- norms + per-slice presum (64 slices) + block scan + inline scanB ----
__global__ __launch_bounds__(256) void norm_scanAB_kernel(
    const unsigned* __restrict__ cnt_sl, float* __restrict__ ns,
    float* __restrict__ nd, int* __restrict__ presum,
    int* __restrict__ pref, int* __restrict__ blk_sum,
    int* __restrict__ blk_ofs, int* __restrict__ done_cnt, int n) {
    __shared__ int lds[256];
    __shared__ int is_last;
    int i = blockIdx.x * 256 + threadIdx.x;
    int d_total = 0;
    if (i < n) {
        int part = (i >= HPN) ? 1 : 0;
        int w = (i - part * HPN) >> 1;
        int sh = (i & 1) * 16;
        int s_total = 0;
        const int bb0 = part * 128;   // hist blocks for this part
#pragma unroll
        for (int sl = 0; sl < NHS; sl++) {
            s_total += (cnt_sl[(size_t)(bb0 + 2 * sl) * HPW + w] >> sh) & 0xffff;
            int c = (cnt_sl[(size_t)(bb0 + 2 * sl + 1) * HPW + w] >> sh) & 0xffff;
            presum[sl * NPAD + i] = d_total;
            d_total += c;
        }
        ns[i] = rsqrtf(fmaxf((float)s_total, 1.0f));
        nd[i] = rsqrtf(fmaxf((float)d_total, 1.0f));
    }
    lds[threadIdx.x] = d_total;
    __syncthreads();
    for (int ofs = 1; ofs < 256; ofs <<= 1) {
        int t = (threadIdx.x >= ofs) ? lds[threadIdx.x - ofs] : 0;
        __syncthreads();
        lds[threadIdx.x] += t;
        __syncthreads();
    }
    if (i < n) pref[i] = lds[threadIdx.x] - d_total;
    if (threadIdx.x == 255) blk_sum[blockIdx.x] = lds[255];
    __threadfence();
    if (threadIdx.x == 0) {
        int c = atomicAdd(done_cnt, 1);
        is_last = (c == gridDim.x - 1);
    }
    __syncthreads();
    if (!is_last) return;
    __threadfence();
    int v = (threadIdx.x < gridDim.x) ? blk_sum[threadIdx.x] : 0;
    __syncthreads();
    lds[threadIdx.x] = v;
    __syncthreads();
    for (int ofs = 1; ofs < 256; ofs <<= 1) {
        int t = (threadIdx.x >= ofs) ? lds[threadIdx.x - ofs] : 0;
        __syncthreads();
        lds[threadIdx.x] += t;
        __syncthreads();
    }
    if (threadIdx.x < gridDim.x) blk_ofs[threadIdx.x] = lds[threadIdx.x] - v;
}

// ---------------- standalone fill (atomic-free CSR, LDS cursors) ------------
// 64 slices x 4 parts = 256 blocks -> exactly 1 block/CU, uncontended.
__global__ __launch_bounds__(1024) void fill_kernel(
    const int* __restrict__ src, const int* __restrict__ dst,
    const int* __restrict__ pref, const int* __restrict__ blk_ofs,
    const int* __restrict__ presum, int* __restrict__ eidx) {
    __shared__ int cur[FPN];
    const int slice = blockIdx.x >> 2;
    const int part = blockIdx.x & 3;
    const int base = part * FPN;
    for (int j = threadIdx.x; j < FPN; j += 1024) {
        int gi = base + j;
        cur[j] = (gi < NN) ? pref[gi] + blk_ofs[gi >> 8] + presum[slice * NPAD + gi] : 0;
    }
    __syncthreads();
    const int e0 = slice * ESL;
    for (int i = e0 + threadIdx.x; i < e0 + ESL; i += 1024) {
        int v = dst[i] - base;
        if ((unsigned)v < (unsigned)FPN) {
            int pos = atomicAdd(&cur[v], 1);
            eidx[pos] = src[i];
        }
    }
}

// ---------------- standalone gemm1: 16 waves x 16 rows, A+B LDS-staged ------
// 196 blocks -> 1 block/CU, uncontended. Per K-chunk stage A tile (32KB,
// XOR-swizzled src) + B frags (Bh 8KB + Bl 8KB) via global_load_lds; compute
// entirely from LDS. hs1[row] = (x @ W1)[row] * norm_src[row] (bf16).
__global__ __launch_bounds__(1024) void gemm1_kernel(
    const float* __restrict__ A, const unsigned short* __restrict__ Wh,
    const unsigned short* __restrict__ Wl, const float* __restrict__ norm_src,
    unsigned short* __restrict__ out, int M) {
    __shared__ __align__(16) char shmem[50176];  // A 32K + Bh 8K + Bl 8K
    constexpr int N = 128, K = 256;
    constexpr int NT = N / 16, KC = K / 32;
    const int wave = threadIdx.x >> 6;       // 0..15
    const int lane = threadIdx.x & 63;
    const int ln = lane & 15;
    const int qk = lane >> 4;
    const int m0 = blockIdx.x * 256 + wave * 16;
    const int m0b = blockIdx.x * 256;
    char* shA = shmem;                        // [256 rows][32 f] swizzled
    char* shB = shmem + 32768;                // Bh 8KB, then Bl 8KB

    // stage chunk c: A = 2048x16B (2/thread, XOR-swizzled source);
    // B = 1024x16B (1/thread: waves 0-7 Bh frag tid, waves 8-15 Bl).
    auto stage = [&](int c) {
#pragma unroll
        for (int h = 0; h < 2; ++h) {
            const int j = threadIdx.x + h * 1024;
            const int row = j >> 3;
            const int sp = (j & 7) ^ (row & 7);
            int grow = m0b + row;
            if (grow >= M) grow = M - 1;
            const float* gp = A + (size_t)grow * K + c * 32 + sp * 4;
            GLOAD_LDS16(gp, shA + (j & ~63) * 16);  // uniform base; HW adds lane*16
        }
        {
            const int j = threadIdx.x & 511;         // frag index within half
            const int t = j >> 6, lfb = (j >> 4) & 3, lnn = j & 15;
            const int fi = ((t * 32 + c * 4 + lfb) * 16 + lnn);  // global frag
            const unsigned short* gsrc =
                (threadIdx.x < 512 ? Wh : Wl) + (size_t)fi * 8;
            char* ldst = shB + (threadIdx.x < 512 ? 0 : 8192) + (j & ~63) * 16;
            GLOAD_LDS16(gsrc, ldst);
        }
    };

    // LDS read offsets (bytes), chunk-independent:
    const int r = wave * 16 + ln;
    const int offA0 = r * 128 + (((qk * 2) ^ (r & 7)) * 16);
    const int offA1 = r * 128 + (((qk * 2 + 1) ^ (r & 7)) * 16);

    f32x4 acc[NT];
#pragma unroll
    for (int t = 0; t < NT; t++) acc[t] = (f32x4){0.f, 0.f, 0.f, 0.f};

#pragma unroll 2
    for (int c = 0; c < KC; ++c) {
        stage(c);
        __syncthreads();   // stage landed (drains vmcnt)
        float4 a0 = *(const float4*)(shA + offA0);  // src floats qk*8..+3
        float4 a1 = *(const float4*)(shA + offA1);  // src floats qk*8+4..+7
        float av[8] = {a0.x, a0.y, a0.z, a0.w, a1.x, a1.y, a1.z, a1.w};
        bf16x8 ah, al;
#pragma unroll
        for (int j = 0; j < 8; ++j) {
            unsigned u = f2u(av[j]);
            float lo = av[j] - u2f(u & 0xffff0000u);
            ah[j] = (short)(u >> 16);
            al[j] = (short)(f2u(lo) >> 16);
        }
#pragma unroll
        for (int t = 0; t < NT; ++t) {
            bf16x8 bh = *(const bf16x8*)(shB + (t * 64 + qk * 16 + ln) * 16);
            bf16x8 bl = *(const bf16x8*)(shB + 8192 + (t * 64 + qk * 16 + ln) * 16);
            acc[t] = __builtin_amdgcn_mfma_f32_16x16x32_bf16(ah, bh, acc[t], 0, 0, 0);
            acc[t] = __builtin_amdgcn_mfma_f32_16x16x32_bf16(ah, bl, acc[t], 0, 0, 0);
            acc[t] = __builtin_amdgcn_mfma_f32_16x16x32_bf16(al, bh, acc[t], 0, 0, 0);
        }
        __syncthreads();   // compute done before next stage overwrites
    }
    float sc[4];
#pragma unroll
    for (int rr = 0; rr < 4; ++rr) {
        int row = m0 + qk * 4 + rr;
        sc[rr] = (row < M) ? norm_src[row] : 0.f;
    }
#pragma unroll
    for (int t = 0; t < NT; ++t)
#pragma unroll
        for (int rr = 0; rr < 4; ++rr) {
            int row = m0 + qk * 4 + rr;
            if (row < M) out[(size_t)row * N + t * 16 + ln] = f2bf(acc[t][rr] * sc[rr]);
        }
}

// -------- fused layer 2 (r3 form): gather(hs1) -> LDS -> bf16 MFMA ----------
__global__ __launch_bounds__(256) void layer2_kernel(
    const unsigned* __restrict__ hs1, const int* __restrict__ eidx,
    const int* __restrict__ pref, const int* __restrict__ blk_ofs,
    const float* __restrict__ norm_src, const float* __restrict__ norm_dst,
    const float* __restrict__ bias, const unsigned short* __restrict__ Wh,
    const unsigned short* __restrict__ Wl, unsigned short* __restrict__ hs2, int n) {
    __shared__ unsigned lh1[16 * 68];
    const int wave = threadIdx.x >> 6;
    const int lane = threadIdx.x & 63;
    const int nb = blockIdx.x * 16;
    const int q = lane >> 4;   // edge slot within 4-edge batch
    const int p = lane & 15;   // dword group: dwords 4p..4p+3 = dims 8p..8p+7

    for (int j = 0; j < 4; ++j) {
        const int node = nb + wave * 4 + j;
        float ax[8];
#pragma unroll
        for (int k = 0; k < 8; ++k) ax[k] = 0.f;
        unsigned pk[4] = {0u, 0u, 0u, 0u};
        if (node < n) {
            int beg = pref[node] + blk_ofs[node >> 8];
            int end = (node + 1 < n) ? pref[node + 1] + blk_ofs[(node + 1) >> 8] : NE;
            int e = beg;
            for (; e + 15 < end; e += 16) {
                int i0 = eidx[e + q];
                int i1 = eidx[e + 4 + q];
                int i2 = eidx[e + 8 + q];
                int i3 = eidx[e + 12 + q];
                uint4 u0 = *(const uint4*)(hs1 + (size_t)i0 * 64 + p * 4);
                uint4 u1 = *(const uint4*)(hs1 + (size_t)i1 * 64 + p * 4);
                uint4 u2 = *(const uint4*)(hs1 + (size_t)i2 * 64 + p * 4);
                uint4 u3 = *(const uint4*)(hs1 + (size_t)i3 * 64 + p * 4);
                acc8(ax, u0);
                acc8(ax, u1);
                acc8(ax, u2);
                acc8(ax, u3);
            }
            for (; e + 7 < end; e += 8) {
                int i0 = eidx[e + q];
                int i1 = eidx[e + 4 + q];
                uint4 u0 = *(const uint4*)(hs1 + (size_t)i0 * 64 + p * 4);
                uint4 u1 = *(const uint4*)(hs1 + (size_t)i1 * 64 + p * 4);
                acc8(ax, u0);
                acc8(ax, u1);
            }
            for (; e < end; e += 4) {     // masked tail (<=1 iter)
                int ee = e + q;
                bool ok = ee < end;
                int i0 = eidx[ok ? ee : beg];
                uint4 u0 = *(const uint4*)(hs1 + (size_t)i0 * 64 + p * 4);
                if (ok) acc8(ax, u0);
            }
#pragma unroll
            for (int k = 0; k < 8; ++k) {
                ax[k] += __shfl_xor(ax[k], 16);
                ax[k] += __shfl_xor(ax[k], 32);
            }
            float sc = norm_dst[node];
            float4 b0 = *(const float4*)(bias + p * 8);
            float4 b1 = *(const float4*)(bias + p * 8 + 4);
            float bb[8] = {b0.x, b0.y, b0.z, b0.w, b1.x, b1.y, b1.z, b1.w};
#pragma unroll
            for (int k = 0; k < 4; ++k) {
                float rlo = fmaxf(ax[2 * k] * sc + bb[2 * k], 0.f);       // relu
                float rhi = fmaxf(ax[2 * k + 1] * sc + bb[2 * k + 1], 0.f);
                pk[k] = (unsigned)f2bf(rlo) | ((unsigned)f2bf(rhi) << 16);
            }
        }
        if (q == 0)
            *(uint4*)&lh1[(wave * 4 + j) * 68 + p * 4] = *(uint4*)pk;
    }
    __syncthreads();

    const int ln = lane & 15;
    const int qk = lane >> 4;
    const int t = wave;
    const bf16x8* BH = (const bf16x8*)Wh;
    const bf16x8* BL = (const bf16x8*)Wl;
    f32x4 acc = (f32x4){0.f, 0.f, 0.f, 0.f};
#pragma unroll
    for (int c = 0; c < 4; ++c) {
        bf16x8 ah = *(const bf16x8*)&lh1[ln * 68 + c * 16 + qk * 4];
        const int fb2 = c * 4 + qk;
        bf16x8 bh = BH[(t * 16 + fb2) * 16 + ln];
        bf16x8 bl = BL[(t * 16 + fb2) * 16 + ln];
        acc = __builtin_amdgcn_mfma_f32_16x16x32_bf16(ah, bh, acc, 0, 0, 0);
        acc = __builtin_amdgcn_mfma_f32_16x16x32_bf16(ah, bl, acc, 0, 0, 0);
    }
#pragma unroll
    for (int r = 0; r < 4; ++r) {
        int node = nb + qk * 4 + r;
        if (node < n)
            hs2[(size_t)node * 64 + t * 16 + ln] = f2bf(acc[r] * norm_src[node]);
    }
}

// ---------------- final gather (D=64, plain sum) + epilogue ----------------
__global__ __launch_bounds__(256) void gather64_kernel(
    const unsigned* __restrict__ hs, const int* __restrict__ eidx,
    const int* __restrict__ pref, const int* __restrict__ blk_ofs,
    const float* __restrict__ norm_dst, const float* __restrict__ bias,
    float* __restrict__ out, int n) {
    int wave = (blockIdx.x * blockDim.x + threadIdx.x) >> 6;
    int lane = threadIdx.x & 63;
    if (wave >= n) return;
    int beg = pref[wave] + blk_ofs[wave >> 8];
    int end = (wave + 1 < n) ? pref[wave + 1] + blk_ofs[(wave + 1) >> 8] : NE;
    const int o = lane >> 3;   // edge slot 0..7
    const int p = lane & 7;    // dword group: dwords 4p..4p+3 = dims 8p..8p+7
    float ax[8];
#pragma unroll
    for (int k = 0; k < 8; ++k) ax[k] = 0.f;
    int e = beg;
    for (; e + 15 < end; e += 16) {
        int i0 = eidx[e + o];
        int i1 = eidx[e + 8 + o];
        uint4 u0 = *(const uint4*)(hs + (size_t)i0 * 32 + p * 4);
        uint4 u1 = *(const uint4*)(hs + (size_t)i1 * 32 + p * 4);
        acc8(ax, u0);
        acc8(ax, u1);
    }
    for (; e < end; e += 8) {         // masked tail (<=2 iters)
        int ee = e + o;
        bool ok = ee < end;
        int i0 = eidx[ok ? ee : beg];
        uint4 u0 = *(const uint4*)(hs + (size_t)i0 * 32 + p * 4);
        if (ok) acc8(ax, u0);
    }
#pragma unroll
    for (int k = 0; k < 8; ++k) {
        ax[k] += __shfl_xor(ax[k], 8);
        ax[k] += __shfl_xor(ax[k], 16);
        ax[k] += __shfl_xor(ax[k], 32);
    }
    if (o == 0) {
        float sc = norm_dst[wave];
        float4 b0 = *(const float4*)(bias + p * 8);
        float4 b1 = *(const float4*)(bias + p * 8 + 4);
        float4 r0, r1;
        r0.x = ax[0] * sc + b0.x;
        r0.y = ax[1] * sc + b0.y;
        r0.z = ax[2] * sc + b0.z;
        r0.w = ax[3] * sc + b0.w;
        r1.x = ax[4] * sc + b1.x;
        r1.y = ax[5] * sc + b1.y;
        r1.z = ax[6] * sc + b1.z;
        r1.w = ax[7] * sc + b1.w;
        *(float4*)(out + (size_t)wave * 64 + p * 8) = r0;
        *(float4*)(out + (size_t)wave * 64 + p * 8 + 4) = r1;
    }
}

extern "C" void kernel_launch(void* const* d_in, const int* in_sizes, int n_in,
                              void* d_out, int out_size, void* d_ws, size_t ws_size,
                              hipStream_t stream) {
    const float* x  = (const float*)d_in[0];   // [50000,256]
    const float* W1 = (const float*)d_in[1];   // [256,128]
    const float* b1 = (const float*)d_in[2];   // [128]
    const float* W2 = (const float*)d_in[3];   // [128,64]
    const float* b2 = (const float*)d_in[4];   // [64]
    const int* src  = (const int*)d_in[5];     // [800000]
    const int* dst  = (const int*)d_in[6];     // [800000]
    float* out = (float*)d_out;                // [50000,64] fp32
    char* ws = (char*)d_ws;

    // ws layout (dword offsets)
    float* norm_src = (float*)(ws);                       // 50176
    float* norm_dst = (float*)(ws + 4 * 50176);           // 50176
    int*   pref     = (int*)(ws + 4 * 100352);            // 50176
    int*   blk_sum  = (int*)(ws + 4 * 150528);            // 256
    int*   blk_ofs  = (int*)(ws + 4 * 150784);            // 256
    int*   done_cnt = (int*)(ws + 4 * 151040);            // 256 (1 used)
    int*   eidx     = (int*)(ws + 4 * 151296);            // 800000
    unsigned short* Wh1 = (unsigned short*)(ws + 4 * 951296);   // 16384 dw
    unsigned short* Wl1 = (unsigned short*)(ws + 4 * 967680);   // 16384 dw
    unsigned short* Wh2 = (unsigned short*)(ws + 4 * 984064);   // 4096 dw
    unsigned short* Wl2 = (unsigned short*)(ws + 4 * 988160);   // 4096 dw
    unsigned short* hs1 = (unsigned short*)(ws + 4 * 992256);   // bf16 [50000,128]
    unsigned short* hs2 = (unsigned short*)(ws + 4 * 4192256);  // bf16 [50000,64]
    unsigned* cnt_sl    = (unsigned*)(ws + 4 * 5792256);        // 256*12544 dw
    int* presum         = (int*)(ws + 4 * 9003520);             // 64*50176 dw
    // end 12,214,784 dw ≈ 48.9 MB (workspace pool is 256 MB)

    hist_wtrans_kernel<<<296, 1024, 0, stream>>>(src, dst, cnt_sl, W1, W2,
                                                 Wh1, Wl1, Wh2, Wl2, done_cnt);

    norm_scanAB_kernel<<<NB, 256, 0, stream>>>(cnt_sl, norm_src, norm_dst,
                                               presum, pref, blk_sum, blk_ofs,
                                               done_cnt, NN);

    fill_kernel<<<FB, 1024, 0, stream>>>(src, dst, pref, blk_ofs, presum, eidx);

    gemm1_kernel<<<GB2, 1024, 0, stream>>>(x, Wh1, Wl1, norm_src, hs1, NN);

    layer2_kernel<<<3125, 256, 0, stream>>>(
        (const unsigned*)hs1, eidx, pref, blk_ofs, norm_src, norm_dst, b1,
        Wh2, Wl2, hs2, NN);

    gather64_kernel<<<12500, 256, 0, stream>>>(
        (const unsigned*)hs2, eidx, pref, blk_ofs, norm_dst, b2, out, NN);
}

// Round 13
// 212.714 us; speedup vs baseline: 1.0437x; 1.0437x over previous
//
#include <hip/hip_runtime.h>

#define NN 50000
#define NE 800000
#define NPAD 50176
// dims: IN=256, HID=128, OUT=64
#define NFS 64        // fill slices (= hist slices)
#define ESL 12500     // NE / NFS (fill)
#define NHS 64        // hist slices
#define EHS 12500     // NE / NHS
#define HPN 25088     // hist nodes per part (2 parts)
#define HPW 12544     // packed words per part (49 KB LDS)
#define FPN 12544     // fill nodes per part (4 parts, 49 KB LDS)
#define FB 256        // fill-role blocks = 64 slices x 4 parts (FIRST in grid)
#define GB2 196       // gemm-role blocks = ceil(NN/256)
#define NB 196        // node blocks = ceil(NN/256)

typedef __attribute__((ext_vector_type(8))) short bf16x8;
typedef __attribute__((ext_vector_type(4))) float f32x4;

__device__ __forceinline__ float u2f(unsigned u) { return __uint_as_float(u); }
__device__ __forceinline__ unsigned f2u(float f) { return __float_as_uint(f); }
__device__ __forceinline__ unsigned short f2bf(float f) {
    unsigned u = f2u(f);
    return (unsigned short)((u + (((u >> 16) & 1u) + 0x7fffu)) >> 16);  // RNE
}
// unpack-accumulate one dword-x4 (8 bf16) into 8 fp32 accumulators
__device__ __forceinline__ void acc8(float* ax, uint4 u) {
    ax[0] += u2f(u.x << 16); ax[1] += u2f(u.x & 0xffff0000u);
    ax[2] += u2f(u.y << 16); ax[3] += u2f(u.y & 0xffff0000u);
    ax[4] += u2f(u.z << 16); ax[5] += u2f(u.z & 0xffff0000u);
    ax[6] += u2f(u.w << 16); ax[7] += u2f(u.w & 0xffff0000u);
}
// async global->LDS 16B (dest = wave-uniform base; HW adds lane*16)
#define GLOAD_LDS16(GP, LP)                                              \
    __builtin_amdgcn_global_load_lds(                                    \
        (const __attribute__((address_space(1))) unsigned*)(GP),         \
        (__attribute__((address_space(3))) unsigned*)(LP), 16, 0, 0)

// ------------- fused: 64-slice packed-ushort LDS histogram + W pre-transform -
// Blocks [0,256): hist role — b = part*128 + slice*2 + side (all 256 CUs).
// Blocks [256,296): wtrans role — fragment-order W1/W2 into bf16 hi/lo.
// Edge scan 4x unrolled: 4 independent loads in flight per trip (MLP).
__global__ __launch_bounds__(1024) void hist_wtrans_kernel(
    const int* __restrict__ src, const int* __restrict__ dst,
    unsigned* __restrict__ cnt_sl,
    const float* __restrict__ W1, const float* __restrict__ W2,
    unsigned short* __restrict__ Wh1, unsigned short* __restrict__ Wl1,
    unsigned short* __restrict__ Wh2, unsigned short* __restrict__ Wl2,
    int* __restrict__ done_cnt) {
    if (blockIdx.x == 0 && threadIdx.x == 0) *done_cnt = 0;  // re-zero each replay
    const int b = blockIdx.x;
    if (b >= 256) {  // wtrans role
        float w;
        unsigned short *ph, *pl;
        int f;
        if (b < 288) {  // W1: K=256, N=128 (32768 elems, 32 blocks)
            int i = (b - 256) * 1024 + threadIdx.x;
            int k = i >> 7, n = i & 127;
            f = (((n >> 4) * 32 + (k >> 3)) * 16 + (n & 15)) * 8 + (k & 7);
            w = W1[i]; ph = Wh1; pl = Wl1;
        } else {        // W2: K=128, N=64 (8192 elems, 8 blocks)
            int i = (b - 288) * 1024 + threadIdx.x;
            int k = i >> 6, n = i & 63;
            f = (((n >> 4) * 16 + (k >> 3)) * 16 + (n & 15)) * 8 + (k & 7);
            w = W2[i]; ph = Wh2; pl = Wl2;
        }
        unsigned u = f2u(w);
        float lo = w - u2f(u & 0xffff0000u);
        ph[f] = (unsigned short)(u >> 16);
        pl[f] = (unsigned short)(f2u(lo) >> 16);
        return;
    }
    // hist role
    __shared__ unsigned lcnt[HPW];
    const int side = b & 1;
    const int slice = (b >> 1) & (NHS - 1);
    const int part = b >> 7;
    const int* __restrict__ arr = side ? dst : src;
    const int base = part * HPN;
    for (int j = threadIdx.x; j < HPW; j += 1024) lcnt[j] = 0;
    __syncthreads();
    const int e0 = slice * EHS, e1 = e0 + EHS;
    int i = e0 + threadIdx.x;
    for (; i + 3072 < e1; i += 4096) {
        int v0 = arr[i] - base;
        int v1 = arr[i + 1024] - base;
        int v2 = arr[i + 2048] - base;
        int v3 = arr[i + 3072] - base;
        if ((unsigned)v0 < (unsigned)HPN) atomicAdd(&lcnt[v0 >> 1], 1u << ((v0 & 1) * 16));
        if ((unsigned)v1 < (unsigned)HPN) atomicAdd(&lcnt[v1 >> 1], 1u << ((v1 & 1) * 16));
        if ((unsigned)v2 < (unsigned)HPN) atomicAdd(&lcnt[v2 >> 1], 1u << ((v2 & 1) * 16));
        if ((unsigned)v3 < (unsigned)HPN) atomicAdd(&lcnt[v3 >> 1], 1u << ((v3 & 1) * 16));
    }
    for (; i < e1; i += 1024) {
        int v = arr[i] - base;
        if ((unsigned)v < (unsigned)HPN)
            atomicAdd(&lcnt[v >> 1], 1u << ((v & 1) * 16));
    }
    __syncthreads();
    unsigned* o = cnt_sl + (size_t)b * HPW;
    for (int j = threadIdx.x; j < HPW; j += 1024) o[j] = lcnt[j];
}

// ------- norms + per-slice presum (64 slices) + block scan + inline scanB ----
__global__ __launch_bounds__(256) void norm_scanAB_kernel(
    const unsigned* __restrict__ cnt_sl, float* __restrict__ ns,
    float* __restrict__ nd, int* __restrict__ presum,
    int* __restrict__ pref, int* __restrict__ blk_sum,
    int* __restrict__ blk_ofs, int* __restrict__ done_cnt, int n) {
    __shared__ int lds[256];
    __shared__ int is_last;
    int i = blockIdx.x * 256 + threadIdx.x;
    int d_total = 0;
    if (i < n) {
        int part = (i >= HPN) ? 1 : 0;
        int w = (i - part * HPN) >> 1;
        int sh = (i & 1) * 16;
        int s_total = 0;
        const int bb0 = part * 128;   // hist blocks for this part
#pragma unroll
        for (int sl = 0; sl < NHS; sl++) {
            s_total += (cnt_sl[(size_t)(bb0 + 2 * sl) * HPW + w] >> sh) & 0xffff;
            int c = (cnt_sl[(size_t)(bb0 + 2 * sl + 1) * HPW + w] >> sh) & 0xffff;
            presum[sl * NPAD + i] = d_total;
            d_total += c;
        }
        ns[i] = rsqrtf(fmaxf((float)s_total, 1.0f));
        nd[i] = rsqrtf(fmaxf((float)d_total, 1.0f));
    }
    lds[threadIdx.x] = d_total;
    __syncthreads();
    for (int ofs = 1; ofs < 256; ofs <<= 1) {
        int t = (threadIdx.x >= ofs) ? lds[threadIdx.x - ofs] : 0;
        __syncthreads();
        lds[threadIdx.x] += t;
        __syncthreads();
    }
    if (i < n) pref[i] = lds[threadIdx.x] - d_total;
    if (threadIdx.x == 255) blk_sum[blockIdx.x] = lds[255];
    __threadfence();
    if (threadIdx.x == 0) {
        int c = atomicAdd(done_cnt, 1);
        is_last = (c == gridDim.x - 1);
    }
    __syncthreads();
    if (!is_last) return;
    __threadfence();
    int v = (threadIdx.x < gridDim.x) ? blk_sum[threadIdx.x] : 0;
    __syncthreads();
    lds[threadIdx.x] = v;
    __syncthreads();
    for (int ofs = 1; ofs < 256; ofs <<= 1) {
        int t = (threadIdx.x >= ofs) ? lds[threadIdx.x - ofs] : 0;
        __syncthreads();
        lds[threadIdx.x] += t;
        __syncthreads();
    }
    if (threadIdx.x < gridDim.x) blk_ofs[threadIdx.x] = lds[threadIdx.x] - v;
}

// ---- merged role-split dispatch @1024 thr: fill [0,256), gemm [256,452) ----
// gemm role: per K-chunk stage A tile (32KB, XOR-swizzled src) + B frags
// (Bh 8KB + Bl 8KB) via global_load_lds; compute entirely from LDS.
// fill role: atomic-free CSR fill, LDS cursors; edge loop 4x unrolled (MLP).
__global__ __launch_bounds__(1024) void gemm1_fill_kernel(
    const float* __restrict__ A, const unsigned short* __restrict__ Wh,
    const unsigned short* __restrict__ Wl, const float* __restrict__ norm_src,
    unsigned short* __restrict__ out,
    const int* __restrict__ src, const int* __restrict__ dst,
    const int* __restrict__ pref, const int* __restrict__ blk_ofs,
    const int* __restrict__ presum, int* __restrict__ eidx, int M) {
    __shared__ __align__(16) char shmem[50176];  // gemm: A 32K + Bh 8K + Bl 8K; fill: cur[FPN]
    const int b = blockIdx.x;
    if (b >= FB) {  // ---------------- gemm role: 16 waves x 16 rows ---------
        const int g = b - FB;
        constexpr int N = 128, K = 256;
        constexpr int NT = N / 16, KC = K / 32;
        const int wave = threadIdx.x >> 6;       // 0..15
        const int lane = threadIdx.x & 63;
        const int ln = lane & 15;
        const int qk = lane >> 4;
        const int m0 = g * 256 + wave * 16;
        const int m0b = g * 256;
        char* shA = shmem;                        // [256 rows][32 f] swizzled
        char* shB = shmem + 32768;                // Bh 8KB, then Bl 8KB

        // stage chunk c: A = 2048x16B (2/thread, XOR-swizzled source);
        // B = 1024x16B (1/thread: waves 0-7 Bh frag tid, waves 8-15 Bl).
        auto stage = [&](int c) {
#pragma unroll
            for (int h = 0; h < 2; ++h) {
                const int j = threadIdx.x + h * 1024;
                const int row = j >> 3;
                const int sp = (j & 7) ^ (row & 7);
                int grow = m0b + row;
                if (grow >= M) grow = M - 1;
                const float* gp = A + (size_t)grow * K + c * 32 + sp * 4;
                GLOAD_LDS16(gp, shA + (j & ~63) * 16);  // uniform base; HW adds lane*16
            }
            {
                const int j = threadIdx.x & 511;         // frag index within half
                const int t = j >> 6, lfb = (j >> 4) & 3, lnn = j & 15;
                const int fi = ((t * 32 + c * 4 + lfb) * 16 + lnn);  // global frag
                const unsigned short* gsrc =
                    (threadIdx.x < 512 ? Wh : Wl) + (size_t)fi * 8;
                char* ldst = shB + (threadIdx.x < 512 ? 0 : 8192) + (j & ~63) * 16;
                GLOAD_LDS16(gsrc, ldst);
            }
        };

        // LDS read offsets (bytes), chunk-independent:
        const int r = wave * 16 + ln;
        const int offA0 = r * 128 + (((qk * 2) ^ (r & 7)) * 16);
        const int offA1 = r * 128 + (((qk * 2 + 1) ^ (r & 7)) * 16);

        f32x4 acc[NT];
#pragma unroll
        for (int t = 0; t < NT; t++) acc[t] = (f32x4){0.f, 0.f, 0.f, 0.f};

#pragma unroll 2
        for (int c = 0; c < KC; ++c) {
            stage(c);
            __syncthreads();   // stage landed (drains vmcnt)
            float4 a0 = *(const float4*)(shA + offA0);  // src floats qk*8..+3
            float4 a1 = *(const float4*)(shA + offA1);  // src floats qk*8+4..+7
            float av[8] = {a0.x, a0.y, a0.z, a0.w, a1.x, a1.y, a1.z, a1.w};
            bf16x8 ah, al;
#pragma unroll
            for (int j = 0; j < 8; ++j) {
                unsigned u = f2u(av[j]);
                float lo = av[j] - u2f(u & 0xffff0000u);
                ah[j] = (short)(u >> 16);
                al[j] = (short)(f2u(lo) >> 16);
            }
#pragma unroll
            for (int t = 0; t < NT; ++t) {
                bf16x8 bh = *(const bf16x8*)(shB + (t * 64 + qk * 16 + ln) * 16);
                bf16x8 bl = *(const bf16x8*)(shB + 8192 + (t * 64 + qk * 16 + ln) * 16);
                acc[t] = __builtin_amdgcn_mfma_f32_16x16x32_bf16(ah, bh, acc[t], 0, 0, 0);
                acc[t] = __builtin_amdgcn_mfma_f32_16x16x32_bf16(ah, bl, acc[t], 0, 0, 0);
                acc[t] = __builtin_amdgcn_mfma_f32_16x16x32_bf16(al, bh, acc[t], 0, 0, 0);
            }
            __syncthreads();   // compute done before next stage overwrites
        }
        float sc[4];
#pragma unroll
        for (int rr = 0; rr < 4; ++rr) {
            int row = m0 + qk * 4 + rr;
            sc[rr] = (row < M) ? norm_src[row] : 0.f;
        }
#pragma unroll
        for (int t = 0; t < NT; ++t)
#pragma unroll
            for (int rr = 0; rr < 4; ++rr) {
                int row = m0 + qk * 4 + rr;
                if (row < M) out[(size_t)row * N + t * 16 + ln] = f2bf(acc[t][rr] * sc[rr]);
            }
        return;
    }
    // ---------------- fill role (atomic-free CSR fill, LDS cursors) ---------
    // 64 slices x 4 parts; 12.5k edges per block; 4x unrolled edge scan.
    int* cur = (int*)shmem;
    const int slice = b >> 2;
    const int part = b & 3;
    const int base = part * FPN;
    for (int j = threadIdx.x; j < FPN; j += 1024) {
        int gi = base + j;
        cur[j] = (gi < NN) ? pref[gi] + blk_ofs[gi >> 8] + presum[slice * NPAD + gi] : 0;
    }
    __syncthreads();
    const int e0 = slice * ESL, e1 = e0 + ESL;
    int i = e0 + threadIdx.x;
    for (; i + 3072 < e1; i += 4096) {
        int v0 = dst[i] - base;
        int v1 = dst[i + 1024] - base;
        int v2 = dst[i + 2048] - base;
        int v3 = dst[i + 3072] - base;
        int s0 = src[i];
        int s1 = src[i + 1024];
        int s2 = src[i + 2048];
        int s3 = src[i + 3072];
        if ((unsigned)v0 < (unsigned)FPN) eidx[atomicAdd(&cur[v0], 1)] = s0;
        if ((unsigned)v1 < (unsigned)FPN) eidx[atomicAdd(&cur[v1], 1)] = s1;
        if ((unsigned)v2 < (unsigned)FPN) eidx[atomicAdd(&cur[v2], 1)] = s2;
        if ((unsigned)v3 < (unsigned)FPN) eidx[atomicAdd(&cur[v3], 1)] = s3;
    }
    for (; i < e1; i += 1024) {
        int v = dst[i] - base;
        if ((unsigned)v < (unsigned)FPN) {
            int pos = atomicAdd(&cur[v], 1);
            eidx[pos] = src[i];
        }
    }
}

// -------- fused layer 2 (r10 form): gather(hs1) -> LDS -> bf16 MFMA ---------
__global__ __launch_bounds__(256) void layer2_kernel(
    const unsigned* __restrict__ hs1, const int* __restrict__ eidx,
    const int* __restrict__ pref, const int* __restrict__ blk_ofs,
    const float* __restrict__ norm_src, const float* __restrict__ norm_dst,
    const float* __restrict__ bias, const unsigned short* __restrict__ Wh,
    const unsigned short* __restrict__ Wl, unsigned short* __restrict__ hs2, int n) {
    __shared__ unsigned lh1[16 * 68];
    const int wave = threadIdx.x >> 6;
    const int lane = threadIdx.x & 63;
    const int nb = blockIdx.x * 16;
    const int q = lane >> 4;   // edge slot within 4-edge batch
    const int p = lane & 15;   // dword group: dwords 4p..4p+3 = dims 8p..8p+7

    for (int j = 0; j < 4; ++j) {
        const int node = nb + wave * 4 + j;
        float ax[8];
#pragma unroll
        for (int k = 0; k < 8; ++k) ax[k] = 0.f;
        unsigned pk[4] = {0u, 0u, 0u, 0u};
        if (node < n) {
            int beg = pref[node] + blk_ofs[node >> 8];
            int end = (node + 1 < n) ? pref[node + 1] + blk_ofs[(node + 1) >> 8] : NE;
            int e = beg;
            for (; e + 15 < end; e += 16) {
                int i0 = eidx[e + q];
                int i1 = eidx[e + 4 + q];
                int i2 = eidx[e + 8 + q];
                int i3 = eidx[e + 12 + q];
                uint4 u0 = *(const uint4*)(hs1 + (size_t)i0 * 64 + p * 4);
                uint4 u1 = *(const uint4*)(hs1 + (size_t)i1 * 64 + p * 4);
                uint4 u2 = *(const uint4*)(hs1 + (size_t)i2 * 64 + p * 4);
                uint4 u3 = *(const uint4*)(hs1 + (size_t)i3 * 64 + p * 4);
                acc8(ax, u0);
                acc8(ax, u1);
                acc8(ax, u2);
                acc8(ax, u3);
            }
            for (; e + 7 < end; e += 8) {
                int i0 = eidx[e + q];
                int i1 = eidx[e + 4 + q];
                uint4 u0 = *(const uint4*)(hs1 + (size_t)i0 * 64 + p * 4);
                uint4 u1 = *(const uint4*)(hs1 + (size_t)i1 * 64 + p * 4);
                acc8(ax, u0);
                acc8(ax, u1);
            }
            for (; e < end; e += 4) {     // masked tail (<=1 iter)
                int ee = e + q;
                bool ok = ee < end;
                int i0 = eidx[ok ? ee : beg];
                uint4 u0 = *(const uint4*)(hs1 + (size_t)i0 * 64 + p * 4);
                if (ok) acc8(ax, u0);
            }
#pragma unroll
            for (int k = 0; k < 8; ++k) {
                ax[k] += __shfl_xor(ax[k], 16);
                ax[k] += __shfl_xor(ax[k], 32);
            }
            float sc = norm_dst[node];
            float4 b0 = *(const float4*)(bias + p * 8);
            float4 b1 = *(const float4*)(bias + p * 8 + 4);
            float bb[8] = {b0.x, b0.y, b0.z, b0.w, b1.x, b1.y, b1.z, b1.w};
#pragma unroll
            for (int k = 0; k < 4; ++k) {
                float rlo = fmaxf(ax[2 * k] * sc + bb[2 * k], 0.f);       // relu
                float rhi = fmaxf(ax[2 * k + 1] * sc + bb[2 * k + 1], 0.f);
                pk[k] = (unsigned)f2bf(rlo) | ((unsigned)f2bf(rhi) << 16);
            }
        }
        if (q == 0)
            *(uint4*)&lh1[(wave * 4 + j) * 68 + p * 4] = *(uint4*)pk;
    }
    __syncthreads();

    const int ln = lane & 15;
    const int qk = lane >> 4;
    const int t = wave;
    const bf16x8* BH = (const bf16x8*)Wh;
    const bf16x8* BL = (const bf16x8*)Wl;
    f32x4 acc = (f32x4){0.f, 0.f, 0.f, 0.f};
#pragma unroll
    for (int c = 0; c < 4; ++c) {
        bf16x8 ah = *(const bf16x8*)&lh1[ln * 68 + c * 16 + qk * 4];
        const int fb2 = c * 4 + qk;
        bf16x8 bh = BH[(t * 16 + fb2) * 16 + ln];
        bf16x8 bl = BL[(t * 16 + fb2) * 16 + ln];
        acc = __builtin_amdgcn_mfma_f32_16x16x32_bf16(ah, bh, acc, 0, 0, 0);
        acc = __builtin_amdgcn_mfma_f32_16x16x32_bf16(ah, bl, acc, 0, 0, 0);
    }
#pragma unroll
    for (int r = 0; r < 4; ++r) {
        int node = nb + qk * 4 + r;
        if (node < n)
            hs2[(size_t)node * 64 + t * 16 + ln] = f2bf(acc[r] * norm_src[node]);
    }
}

// ---------------- final gather (D=64, plain sum) + epilogue ----------------
__global__ __launch_bounds__(256) void gather64_kernel(
    const unsigned* __restrict__ hs, const int* __restrict__ eidx,
    const int* __restrict__ pref, const int* __restrict__ blk_ofs,
    const float* __restrict__ norm_dst, const float* __restrict__ bias,
    float* __restrict__ out, int n) {
    int wave = (blockIdx.x * blockDim.x + threadIdx.x) >> 6;
    int lane = threadIdx.x & 63;
    if (wave >= n) return;
    int beg = pref[wave] + blk_ofs[wave >> 8];
    int end = (wave + 1 < n) ? pref[wave + 1] + blk_ofs[(wave + 1) >> 8] : NE;
    const int o = lane >> 3;   // edge slot 0..7
    const int p = lane & 7;    // dword group: dwords 4p..4p+3 = dims 8p..8p+7
    float ax[8];
#pragma unroll
    for (int k = 0; k < 8; ++k) ax[k] = 0.f;
    int e = beg;
    for (; e + 15 < end; e += 16) {
        int i0 = eidx[e + o];
        int i1 = eidx[e + 8 + o];
        uint4 u0 = *(const uint4*)(hs + (size_t)i0 * 32 + p * 4);
        uint4 u1 = *(const uint4*)(hs + (size_t)i1 * 32 + p * 4);
        acc8(ax, u0);
        acc8(ax, u1);
    }
    for (; e < end; e += 8) {         // masked tail (<=2 iters)
        int ee = e + o;
        bool ok = ee < end;
        int i0 = eidx[ok ? ee : beg];
        uint4 u0 = *(const uint4*)(hs + (size_t)i0 * 32 + p * 4);
        if (ok) acc8(ax, u0);
    }
#pragma unroll
    for (int k = 0; k < 8; ++k) {
        ax[k] += __shfl_xor(ax[k], 8);
        ax[k] += __shfl_xor(ax[k], 16);
        ax[k] += __shfl_xor(ax[k], 32);
    }
    if (o == 0) {
        float sc = norm_dst[wave];
        float4 b0 = *(const float4*)(bias + p * 8);
        float4 b1 = *(const float4*)(bias + p * 8 + 4);
        float4 r0, r1;
        r0.x = ax[0] * sc + b0.x;
        r0.y = ax[1] * sc + b0.y;
        r0.z = ax[2] * sc + b0.z;
        r0.w = ax[3] * sc + b0.w;
        r1.x = ax[4] * sc + b1.x;
        r1.y = ax[5] * sc + b1.y;
        r1.z = ax[6] * sc + b1.z;
        r1.w = ax[7] * sc + b1.w;
        *(float4*)(out + (size_t)wave * 64 + p * 8) = r0;
        *(float4*)(out + (size_t)wave * 64 + p * 8 + 4) = r1;
    }
}

extern "C" void kernel_launch(void* const* d_in, const int* in_sizes, int n_in,
                              void* d_out, int out_size, void* d_ws, size_t ws_size,
                              hipStream_t stream) {
    const float* x  = (const float*)d_in[0];   // [50000,256]
    const float* W1 = (const float*)d_in[1];   // [256,128]
    const float* b1 = (const float*)d_in[2];   // [128]
    const float* W2 = (const float*)d_in[3];   // [128,64]
    const float* b2 = (const float*)d_in[4];   // [64]
    const int* src  = (const int*)d_in[5];     // [800000]
    const int* dst  = (const int*)d_in[6];     // [800000]
    float* out = (float*)d_out;                // [50000,64] fp32
    char* ws = (char*)d_ws;

    // ws layout (dword offsets)
    float* norm_src = (float*)(ws);                       // 50176
    float* norm_dst = (float*)(ws + 4 * 50176);           // 50176
    int*   pref     = (int*)(ws + 4 * 100352);            // 50176
    int*   blk_sum  = (int*)(ws + 4 * 150528);            // 256
    int*   blk_ofs  = (int*)(ws + 4 * 150784);            // 256
    int*   done_cnt = (int*)(ws + 4 * 151040);            // 256 (1 used)
    int*   eidx     = (int*)(ws + 4 * 151296);            // 800000
    unsigned short* Wh1 = (unsigned short*)(ws + 4 * 951296);   // 16384 dw
    unsigned short* Wl1 = (unsigned short*)(ws + 4 * 967680);   // 16384 dw
    unsigned short* Wh2 = (unsigned short*)(ws + 4 * 984064);   // 4096 dw
    unsigned short* Wl2 = (unsigned short*)(ws + 4 * 988160);   // 4096 dw
    unsigned short* hs1 = (unsigned short*)(ws + 4 * 992256);   // bf16 [50000,128]
    unsigned short* hs2 = (unsigned short*)(ws + 4 * 4192256);  // bf16 [50000,64]
    unsigned* cnt_sl    = (unsigned*)(ws + 4 * 5792256);        // 256*12544 dw
    int* presum         = (int*)(ws + 4 * 9003520);             // 64*50176 dw
    // end 12,214,784 dw ≈ 48.9 MB (workspace pool is 256 MB)

    hist_wtrans_kernel<<<296, 1024, 0, stream>>>(src, dst, cnt_sl, W1, W2,
                                                 Wh1, Wl1, Wh2, Wl2, done_cnt);

    norm_scanAB_kernel<<<NB, 256, 0, stream>>>(cnt_sl, norm_src, norm_dst,
                                               presum, pref, blk_sum, blk_ofs,
                                               done_cnt, NN);

    gemm1_fill_kernel<<<FB + GB2, 1024, 0, stream>>>(
        x, Wh1, Wl1, norm_src, hs1, src, dst, pref, blk_ofs, presum, eidx, NN);

    layer2_kernel<<<3125, 256, 0, stream>>>(
        (const unsigned*)hs1, eidx, pref, blk_ofs, norm_src, norm_dst, b1,
        Wh2, Wl2, hs2, NN);

    gather64_kernel<<<12500, 256, 0, stream>>>(
        (const unsigned*)hs2, eidx, pref, blk_ofs, norm_dst, b2, out, NN);
}